// Round 15
// baseline (815.457 us; speedup 1.0000x reference)
//
#include <hip/hip_runtime.h>
#include <hip/hip_bf16.h>

#define T_DIM 256
#define B_DIM 128
#define C_DIM 1024
#define H_DIM 1024
#define L_DIM 6
#define NC_DIM 1000
#define M_DIM (T_DIM * B_DIM)    // 32768
#define BH_DIM (B_DIM * H_DIM)   // 131072

typedef __attribute__((ext_vector_type(8))) short bf16x8;
typedef __attribute__((ext_vector_type(4))) float f32x4;

__device__ __forceinline__ float bf2f(unsigned short u) {
  union { unsigned int i; float f; } v; v.i = ((unsigned int)u) << 16; return v.f;
}
__device__ __forceinline__ unsigned short f2bf(float f) {
  union { float f; unsigned int i; } v; v.f = f;
  unsigned int r = v.i + 0x7fffu + ((v.i >> 16) & 1u);  // RNE
  return (unsigned short)(r >> 16);
}
__device__ __forceinline__ unsigned int pack2bf(float lo, float hi) {
  __hip_bfloat162 b2 = __float22bfloat162_rn(float2{lo, hi});
  union { __hip_bfloat162 b; unsigned int u; } cv; cv.b = b2; return cv.u;
}

__device__ __forceinline__ void gload_lds16(const void* g, void* l) {
  __builtin_amdgcn_global_load_lds(
      (const __attribute__((address_space(1))) unsigned int*)g,
      (__attribute__((address_space(3))) unsigned int*)l, 16, 0, 0);
}

// ---------------- x f32 -> bf16 convert ----------------
__global__ __launch_bounds__(256) void f32_to_bf16_kernel(
    const float* __restrict__ in, unsigned short* __restrict__ out, int n4) {
  int stride = gridDim.x * blockDim.x;
  for (int i = blockIdx.x * blockDim.x + threadIdx.x; i < n4; i += stride) {
    float4 v = ((const float4*)in)[i];
    uint2 o; o.x = pack2bf(v.x, v.y); o.y = pack2bf(v.z, v.w);
    ((uint2*)out)[i] = o;
  }
}

// ---------------- W (L,C,H) f32 -> Wt (L,H,C) bf16 ----------------
__global__ __launch_bounds__(256) void wtrans_kernel(
    const float* __restrict__ W, unsigned short* __restrict__ Wt) {
  __shared__ float tile[32][33];
  int l = blockIdx.z;
  const float* Wl = W + (size_t)l * C_DIM * H_DIM;
  unsigned short* Wtl = Wt + (size_t)l * C_DIM * H_DIM;
  int h0 = blockIdx.x * 32, c0 = blockIdx.y * 32;
  int tx = threadIdx.x, ty = threadIdx.y;  // 32 x 8
#pragma unroll
  for (int i = 0; i < 32; i += 8)
    tile[ty + i][tx] = Wl[(size_t)(c0 + ty + i) * H_DIM + h0 + tx];
  __syncthreads();
#pragma unroll
  for (int i = 0; i < 32; i += 8)
    Wtl[(size_t)(h0 + ty + i) * C_DIM + c0 + tx] = f2bf(tile[tx][ty + i]);
}

// ---------------- GEMM 256x256, BK=32, 4-buffer pipeline, 2 tiles/block ----------------
// (round-11 kernel, unchanged: established ~900 TF plain-HIP structure ceiling)
#define NT 32  // K / 32

__global__ __launch_bounds__(512, 2) void gemm_kernel(
    const unsigned short* __restrict__ A, const unsigned short* __restrict__ Bt,
    unsigned short* __restrict__ Z, float* __restrict__ psum, float* __restrict__ psqs) {
  extern __shared__ char lds[];
  int bid = blockIdx.x;              // 256 blocks, %8==0 -> bijective XCD swizzle
  int swz = (bid & 7) * 32 + (bid >> 3);
  int tm0 = (swz >> 2) * 2;          // tiles (tm0, tn) and (tm0+1, tn)
  int tn = swz & 3;
  int tid = threadIdx.x;
  int wv = tid >> 6, ln = tid & 63;
  int wm = wv >> 2, wn = wv & 3;     // 2 x 4 wave grid

  const char* Ap0 = (const char*)A + (size_t)tm0 * 256 * 2048;        // 2048B = K row
  const char* Ap1 = Ap0 + (size_t)256 * 2048;
  const char* Bpanel = (const char*)Bt + (size_t)tn * 256 * 2048;

  int p0 = wv * 1024 + ln * 16;           // byte within an 8KB (128-row) half
  int l0 = p0 ^ (((p0 >> 7) & 3) << 4);   // involution: chunk ^= (row>>1)&3
  size_t ro0 = (size_t)(p0 >> 6) * 2048 + (l0 & 63);          // rows 0..127
  size_t ro1 = (size_t)(128 + (p0 >> 6)) * 2048 + (l0 & 63);  // rows 128..255
  int sdst = wv * 1024;                   // wave-uniform (+ lane*16 by HW)

  auto stage = [&](const char* Ap, int t) {  // one 32KB K-tile: A 16KB + B 16KB
    char* base = lds + ((t & 3) * 32768);
    int kb = t * 64;                      // 32 k-elems = 64 bytes
    gload_lds16(Ap + ro0 + kb, base + sdst);
    gload_lds16(Ap + ro1 + kb, base + 8192 + sdst);
    gload_lds16(Bpanel + ro0 + kb, base + 16384 + sdst);
    gload_lds16(Bpanel + ro1 + kb, base + 16384 + 8192 + sdst);
  };

  int frow = ln & 15;
  int fchunk = ((ln >> 4) ^ (frow >> 1)) & 3;
  int floff = frow * 64 + (fchunk << 4);

  f32x4 acc[8][4];

  bf16x8 bX[4], aP[4], aQ[4];
  auto readB_to = [&](int t, bf16x8* d) {
    const char* Bb = lds + ((t & 3) * 32768) + 16384 + wn * 4096;
#pragma unroll
    for (int n = 0; n < 4; ++n) d[n] = *(const bf16x8*)(Bb + n * 1024 + floff);
  };
  auto readA_to = [&](int t, int mq, bf16x8* d) {
    const char* Ab = lds + ((t & 3) * 32768) + wm * 8192 + mq * 4096;
#pragma unroll
    for (int i = 0; i < 4; ++i) d[i] = *(const bf16x8*)(Ab + i * 1024 + floff);
  };

  auto kloop = [&](const char* Ap) {
    f32x4 zero = {0.f, 0.f, 0.f, 0.f};
#pragma unroll
    for (int m = 0; m < 8; ++m)
#pragma unroll
      for (int n = 0; n < 4; ++n) acc[m][n] = zero;
    readB_to(0, bX); readA_to(0, 0, aP);
    for (int t = 0; t < NT; ++t) {
      readA_to(t, 1, aQ);                  // batch1: overlaps cluster0 below
      if (t <= NT - 4) stage(Ap, t + 3);
      __builtin_amdgcn_s_setprio(1);
#pragma unroll
      for (int i = 0; i < 4; ++i)
#pragma unroll
        for (int n = 0; n < 4; ++n)
          acc[i][n] = __builtin_amdgcn_mfma_f32_16x16x32_bf16(aP[i], bX[n], acc[i][n], 0, 0, 0);
      __builtin_amdgcn_s_setprio(0);
      __builtin_amdgcn_s_setprio(1);
#pragma unroll
      for (int i = 0; i < 4; ++i)
#pragma unroll
        for (int n = 0; n < 4; ++n)
          acc[4 + i][n] = __builtin_amdgcn_mfma_f32_16x16x32_bf16(aQ[i], bX[n], acc[4 + i][n], 0, 0, 0);
      __builtin_amdgcn_s_setprio(0);
      if (t < NT - 1) {
        readB_to(t + 1, bX); readA_to(t + 1, 0, aP);   // batch0(t+1)
        if (t <= NT - 4) { asm volatile("s_waitcnt vmcnt(4)" ::: "memory"); }
        else             { asm volatile("s_waitcnt vmcnt(0)" ::: "memory"); }
        __builtin_amdgcn_s_barrier();      // staging(t+2) visible
      }
    }
  };

  float* red = (float*)(lds + 3 * 32768);  // buffer-3 region
  auto epilogue = [&](int tm) {
    float s[4], q[4];
#pragma unroll
    for (int n = 0; n < 4; ++n) {
      float sv = 0.f, qv = 0.f;
#pragma unroll
      for (int m = 0; m < 8; ++m)
#pragma unroll
        for (int r = 0; r < 4; ++r) {
          float v = acc[m][n][r];
          sv += v; qv += v * v;
        }
      s[n] = sv; q[n] = qv;
    }
#pragma unroll
    for (int n = 0; n < 4; ++n) {
      s[n] += __shfl_xor(s[n], 16); s[n] += __shfl_xor(s[n], 32);
      q[n] += __shfl_xor(q[n], 16); q[n] += __shfl_xor(q[n], 32);
    }
    if (ln < 16) {
#pragma unroll
      for (int n = 0; n < 4; ++n) {
        red[wm * 256 + wn * 64 + n * 16 + ln] = s[n];
        red[512 + wm * 256 + wn * 64 + n * 16 + ln] = q[n];
      }
    }
    __syncthreads();
    if (tid < 256) {
      psum[(size_t)tm * H_DIM + tn * 256 + tid] = red[tid] + red[256 + tid];
    } else {
      int c = tid - 256;
      psqs[(size_t)tm * H_DIM + tn * 256 + c] = red[512 + c] + red[768 + c];
    }
    __syncthreads();   // red consumed; safe for next tile's reuse
    int r0 = tm * 256 + wm * 128 + ((ln >> 4) << 2);
    int c0 = tn * 256 + wn * 64 + (ln & 15);
#pragma unroll
    for (int m = 0; m < 8; ++m)
#pragma unroll
      for (int n = 0; n < 4; ++n) {
        unsigned short* zp = Z + (size_t)(r0 + m * 16) * H_DIM + c0 + n * 16;
#pragma unroll
        for (int r = 0; r < 4; ++r) zp[(size_t)r * H_DIM] = f2bf(acc[m][n][r]);
      }
  };

  // ---- tile 1 ----
  stage(Ap0, 0); stage(Ap0, 1); stage(Ap0, 2);
  asm volatile("s_waitcnt vmcnt(4)" ::: "memory");
  __builtin_amdgcn_s_barrier();
  kloop(Ap0);
  __builtin_amdgcn_s_barrier();            // all reads of bufs done
  // ---- tile 2 staging overlapped with tile-1 epilogue ----
  stage(Ap1, 0); stage(Ap1, 1); stage(Ap1, 2);
  epilogue(tm0);
  asm volatile("s_waitcnt vmcnt(4)" ::: "memory");  // 12 loads (+most stores) retired
  __builtin_amdgcn_s_barrier();
  kloop(Ap1);
  __builtin_amdgcn_s_barrier();
  epilogue(tm0 + 1);
}

// ---------------- BN finalize: sum 128 partials per channel ----------------
__global__ __launch_bounds__(256) void bn_finalize_kernel(
    const float* __restrict__ psum, const float* __restrict__ psqs,
    const float* __restrict__ gamma, const float* __restrict__ beta,
    float* __restrict__ ss) {
  int c = blockIdx.x * blockDim.x + threadIdx.x;
  float s = 0.f, q = 0.f;
#pragma unroll 8
  for (int i = 0; i < 128; ++i) {
    s += psum[(size_t)i * H_DIM + c];
    q += psqs[(size_t)i * H_DIM + c];
  }
  const float invN = 1.0f / (float)M_DIM;
  float mean = s * invN;
  float var = q * invN - mean * mean;
  float sc = gamma[c] * rsqrtf(var + 1e-5f);
  ss[c] = sc;
  ss[H_DIM + c] = beta[c] - mean * sc;
}

// ---------------- fused BN-apply + IndRNN recurrence, LDS-staged 16B/lane HBM ----------------
// Block = 256 consecutive channel-pairs (1KB per t-row); 256 blocks, 256 threads.
// Per 32-t chunk: global_load_lds dwordx4 stages the 32KB Z-slab (16B/lane,
// fully coalesced) -> threads run 32 recurrence steps reading LDS at 4B stride-1
// (conflict-free) and writing to an LDS out-slab -> waves burst-store the slab
// with dwordx4 (16B/lane). Double-buffered in-slabs; counted vmcnt(8) per chunk
// (retirement order: newest 8 = this chunk's 8 stores => stage(c+1) landed).
// FULL=0 (last layer): store only the t=255 row - the only slice consumed.
__global__ __launch_bounds__(256) void bn_recur_kernel(
    const unsigned short* __restrict__ Z, const float* __restrict__ ss,
    const float* __restrict__ u, unsigned short* __restrict__ Hout, int full) {
  __shared__ char sbuf[98304];               // in0 32KB | in1 32KB | out 32KB
  char* in0 = sbuf;
  char* in1 = sbuf + 32768;
  char* outb = sbuf + 65536;
  int blk = blockIdx.x;
  int tid = threadIdx.x;
  int wv = tid >> 6, ln = tid & 63;

  int h0 = ((blk * 256 + tid) & (H_DIM / 2 - 1)) * 2;
  float sc0 = ss[h0], sc1 = ss[h0 + 1];
  float sh0 = ss[H_DIM + h0], sh1 = ss[H_DIM + h0 + 1];
  float u0 = u[h0], u1 = u[h0 + 1];
  float hv0 = 0.f, hv1 = 0.f;

  const char* Zb = (const char*)Z + (size_t)blk * 1024;   // row stride 256KB
  char* Hb = (char*)Hout + (size_t)blk * 1024;
  const size_t ROWB = (size_t)BH_DIM * 2;    // 262144 bytes per t

  auto stage = [&](int c) {                  // 32KB slab: 8 gload_lds/wave
    char* dst = (c & 1) ? in1 : in0;
    int t0 = c * 32;
#pragma unroll
    for (int j = 0; j < 8; ++j) {
      int r = wv * 8 + j;
      gload_lds16(Zb + (size_t)(t0 + r) * ROWB + ln * 16, dst + r * 1024);
    }
  };

  stage(0);
  asm volatile("s_waitcnt vmcnt(0)" ::: "memory");
  __builtin_amdgcn_s_barrier();

  for (int c = 0; c < 8; ++c) {
    if (c < 7) stage(c + 1);
    const char* inb = (c & 1) ? in1 : in0;
    // ---- 32 recurrence steps from LDS (4B stride-1: conflict-free) ----
#pragma unroll
    for (int t = 0; t < 32; ++t) {
      unsigned int zz = *(const unsigned int*)(inb + t * 1024 + tid * 4);
      float z0 = fmaf(bf2f((unsigned short)(zz & 0xffffu)), sc0, sh0);
      float z1 = fmaf(bf2f((unsigned short)(zz >> 16)), sc1, sh1);
      hv0 = fmaxf(fmaf(u0, hv0, z0), 0.f);
      hv1 = fmaxf(fmaf(u1, hv1, z1), 0.f);
      *(unsigned int*)(outb + t * 1024 + tid * 4) = pack2bf(hv0, hv1);
    }
    asm volatile("s_waitcnt lgkmcnt(0)" ::: "memory");
    __builtin_amdgcn_s_barrier();            // out slab complete & visible
    // ---- burst store: 8 x (ds_read_b128 + global_store_dwordx4) per wave ----
    int t0 = c * 32;
#pragma unroll
    for (int j = 0; j < 8; ++j) {
      int r = wv * 8 + j;
      if (full || (c == 7 && r == 31)) {
        uint4 v = *(const uint4*)(outb + r * 1024 + ln * 16);
        *(uint4*)(Hb + (size_t)(t0 + r) * ROWB + ln * 16) = v;
      }
    }
    if (c < 7) {
      // out-slab ds_reads done (lgkm) + stage(c+1) landed (vmcnt: newest 8 =
      // this chunk's stores; full=0 issues no stores -> wait all)
      if (full) { asm volatile("s_waitcnt lgkmcnt(0) vmcnt(8)" ::: "memory"); }
      else      { asm volatile("s_waitcnt lgkmcnt(0) vmcnt(0)" ::: "memory"); }
      __builtin_amdgcn_s_barrier();
    }
  }
}

// ---------------- classifier ----------------
__global__ __launch_bounds__(256) void classifier_kernel(
    const unsigned short* __restrict__ hlast, const float* __restrict__ Wc,
    const float* __restrict__ bc, float* __restrict__ out) {
  __shared__ float hs[H_DIM];
  int b = blockIdx.y;
  int n = blockIdx.x * 256 + threadIdx.x;
  for (int k = threadIdx.x; k < H_DIM; k += 256)
    hs[k] = bf2f(hlast[(size_t)b * H_DIM + k]);
  __syncthreads();
  if (n < NC_DIM) {
    float acc = bc[n];
#pragma unroll 8
    for (int k = 0; k < H_DIM; ++k)
      acc = fmaf(hs[k], Wc[(size_t)k * NC_DIM + n], acc);
    out[(size_t)b * NC_DIM + n] = acc;
  }
}

extern "C" void kernel_launch(void* const* d_in, const int* in_sizes, int n_in,
                              void* d_out, int out_size, void* d_ws, size_t ws_size,
                              hipStream_t stream) {
  const float* x     = (const float*)d_in[0];
  const float* W     = (const float*)d_in[1];
  // d_in[2] = b: cancels under BatchNorm (shift-invariant)
  const float* gamma = (const float*)d_in[3];
  const float* beta  = (const float*)d_in[4];
  const float* u     = (const float*)d_in[5];
  const float* Wc    = (const float*)d_in[6];
  const float* bc    = (const float*)d_in[7];
  float* out = (float*)d_out;

  const size_t CH = (size_t)C_DIM * H_DIM;
  const size_t MH = (size_t)M_DIM * H_DIM;
  char* p = (char*)d_ws;
  unsigned short* Wt = (unsigned short*)p; p += L_DIM * CH * sizeof(unsigned short);
  unsigned short* Ha = (unsigned short*)p; p += MH * sizeof(unsigned short);
  unsigned short* Hb = (unsigned short*)p; p += MH * sizeof(unsigned short);
  unsigned short* Z  = (unsigned short*)p; p += MH * sizeof(unsigned short);
  float* psum = (float*)p; p += 128 * H_DIM * sizeof(float);
  float* psqs = (float*)p; p += 128 * H_DIM * sizeof(float);
  float* ss   = (float*)p; p += 2 * H_DIM * sizeof(float);

  f32_to_bf16_kernel<<<2048, 256, 0, stream>>>(x, Ha, (int)(MH / 4));
  wtrans_kernel<<<dim3(H_DIM / 32, C_DIM / 32, L_DIM), dim3(32, 8), 0, stream>>>(W, Wt);

  unsigned short* cur = Ha;
  unsigned short* nxt = Hb;
  for (int l = 0; l < L_DIM; ++l) {
    gemm_kernel<<<256, 512, 131072, stream>>>(cur, Wt + (size_t)l * CH, Z, psum, psqs);
    bn_finalize_kernel<<<4, 256, 0, stream>>>(psum, psqs, gamma + (size_t)l * H_DIM,
                                              beta + (size_t)l * H_DIM, ss);
    bn_recur_kernel<<<256, 256, 0, stream>>>(Z, ss, u + (size_t)l * H_DIM, nxt,
                                             (l < L_DIM - 1) ? 1 : 0);
    unsigned short* tmp = cur; cur = nxt; nxt = tmp;
  }
  classifier_kernel<<<dim3(4, B_DIM), 256, 0, stream>>>(
      cur + (size_t)(T_DIM - 1) * BH_DIM, Wc, bc, out);
}

// Round 16
// 752.504 us; speedup vs baseline: 1.0837x; 1.0837x over previous
//
#include <hip/hip_runtime.h>
#include <hip/hip_bf16.h>

#define T_DIM 256
#define B_DIM 128
#define C_DIM 1024
#define H_DIM 1024
#define L_DIM 6
#define NC_DIM 1000
#define M_DIM (T_DIM * B_DIM)    // 32768
#define BH_DIM (B_DIM * H_DIM)   // 131072

typedef __attribute__((ext_vector_type(8))) short bf16x8;
typedef __attribute__((ext_vector_type(4))) float f32x4;

__device__ __forceinline__ float bf2f(unsigned short u) {
  union { unsigned int i; float f; } v; v.i = ((unsigned int)u) << 16; return v.f;
}
__device__ __forceinline__ unsigned short f2bf(float f) {
  union { float f; unsigned int i; } v; v.f = f;
  unsigned int r = v.i + 0x7fffu + ((v.i >> 16) & 1u);  // RNE
  return (unsigned short)(r >> 16);
}
__device__ __forceinline__ unsigned int pack2bf(float lo, float hi) {
  __hip_bfloat162 b2 = __float22bfloat162_rn(float2{lo, hi});
  union { __hip_bfloat162 b; unsigned int u; } cv; cv.b = b2; return cv.u;
}

__device__ __forceinline__ void gload_lds16(const void* g, void* l) {
  __builtin_amdgcn_global_load_lds(
      (const __attribute__((address_space(1))) unsigned int*)g,
      (__attribute__((address_space(3))) unsigned int*)l, 16, 0, 0);
}

// ---------------- x f32 -> bf16 convert ----------------
__global__ __launch_bounds__(256) void f32_to_bf16_kernel(
    const float* __restrict__ in, unsigned short* __restrict__ out, int n4) {
  int stride = gridDim.x * blockDim.x;
  for (int i = blockIdx.x * blockDim.x + threadIdx.x; i < n4; i += stride) {
    float4 v = ((const float4*)in)[i];
    uint2 o; o.x = pack2bf(v.x, v.y); o.y = pack2bf(v.z, v.w);
    ((uint2*)out)[i] = o;
  }
}

// ---------------- W (L,C,H) f32 -> Wt (L,H,C) bf16 ----------------
__global__ __launch_bounds__(256) void wtrans_kernel(
    const float* __restrict__ W, unsigned short* __restrict__ Wt) {
  __shared__ float tile[32][33];
  int l = blockIdx.z;
  const float* Wl = W + (size_t)l * C_DIM * H_DIM;
  unsigned short* Wtl = Wt + (size_t)l * C_DIM * H_DIM;
  int h0 = blockIdx.x * 32, c0 = blockIdx.y * 32;
  int tx = threadIdx.x, ty = threadIdx.y;  // 32 x 8
#pragma unroll
  for (int i = 0; i < 32; i += 8)
    tile[ty + i][tx] = Wl[(size_t)(c0 + ty + i) * H_DIM + h0 + tx];
  __syncthreads();
#pragma unroll
  for (int i = 0; i < 32; i += 8)
    Wtl[(size_t)(h0 + ty + i) * C_DIM + c0 + tx] = f2bf(tile[tx][ty + i]);
}

// ---------------- GEMM 256x256, BK=32, 4-buffer pipeline, 2 tiles/block ----------------
// (round-11 kernel, unchanged: established ~900 TF plain-HIP structure ceiling)
#define NT 32  // K / 32

__global__ __launch_bounds__(512, 2) void gemm_kernel(
    const unsigned short* __restrict__ A, const unsigned short* __restrict__ Bt,
    unsigned short* __restrict__ Z, float* __restrict__ psum, float* __restrict__ psqs) {
  extern __shared__ char lds[];
  int bid = blockIdx.x;              // 256 blocks, %8==0 -> bijective XCD swizzle
  int swz = (bid & 7) * 32 + (bid >> 3);
  int tm0 = (swz >> 2) * 2;          // tiles (tm0, tn) and (tm0+1, tn)
  int tn = swz & 3;
  int tid = threadIdx.x;
  int wv = tid >> 6, ln = tid & 63;
  int wm = wv >> 2, wn = wv & 3;     // 2 x 4 wave grid

  const char* Ap0 = (const char*)A + (size_t)tm0 * 256 * 2048;        // 2048B = K row
  const char* Ap1 = Ap0 + (size_t)256 * 2048;
  const char* Bpanel = (const char*)Bt + (size_t)tn * 256 * 2048;

  int p0 = wv * 1024 + ln * 16;           // byte within an 8KB (128-row) half
  int l0 = p0 ^ (((p0 >> 7) & 3) << 4);   // involution: chunk ^= (row>>1)&3
  size_t ro0 = (size_t)(p0 >> 6) * 2048 + (l0 & 63);          // rows 0..127
  size_t ro1 = (size_t)(128 + (p0 >> 6)) * 2048 + (l0 & 63);  // rows 128..255
  int sdst = wv * 1024;                   // wave-uniform (+ lane*16 by HW)

  auto stage = [&](const char* Ap, int t) {  // one 32KB K-tile: A 16KB + B 16KB
    char* base = lds + ((t & 3) * 32768);
    int kb = t * 64;                      // 32 k-elems = 64 bytes
    gload_lds16(Ap + ro0 + kb, base + sdst);
    gload_lds16(Ap + ro1 + kb, base + 8192 + sdst);
    gload_lds16(Bpanel + ro0 + kb, base + 16384 + sdst);
    gload_lds16(Bpanel + ro1 + kb, base + 16384 + 8192 + sdst);
  };

  int frow = ln & 15;
  int fchunk = ((ln >> 4) ^ (frow >> 1)) & 3;
  int floff = frow * 64 + (fchunk << 4);

  f32x4 acc[8][4];

  bf16x8 bX[4], aP[4], aQ[4];
  auto readB_to = [&](int t, bf16x8* d) {
    const char* Bb = lds + ((t & 3) * 32768) + 16384 + wn * 4096;
#pragma unroll
    for (int n = 0; n < 4; ++n) d[n] = *(const bf16x8*)(Bb + n * 1024 + floff);
  };
  auto readA_to = [&](int t, int mq, bf16x8* d) {
    const char* Ab = lds + ((t & 3) * 32768) + wm * 8192 + mq * 4096;
#pragma unroll
    for (int i = 0; i < 4; ++i) d[i] = *(const bf16x8*)(Ab + i * 1024 + floff);
  };

  auto kloop = [&](const char* Ap) {
    f32x4 zero = {0.f, 0.f, 0.f, 0.f};
#pragma unroll
    for (int m = 0; m < 8; ++m)
#pragma unroll
      for (int n = 0; n < 4; ++n) acc[m][n] = zero;
    readB_to(0, bX); readA_to(0, 0, aP);
    for (int t = 0; t < NT; ++t) {
      readA_to(t, 1, aQ);                  // batch1: overlaps cluster0 below
      if (t <= NT - 4) stage(Ap, t + 3);
      __builtin_amdgcn_s_setprio(1);
#pragma unroll
      for (int i = 0; i < 4; ++i)
#pragma unroll
        for (int n = 0; n < 4; ++n)
          acc[i][n] = __builtin_amdgcn_mfma_f32_16x16x32_bf16(aP[i], bX[n], acc[i][n], 0, 0, 0);
      __builtin_amdgcn_s_setprio(0);
      __builtin_amdgcn_s_setprio(1);
#pragma unroll
      for (int i = 0; i < 4; ++i)
#pragma unroll
        for (int n = 0; n < 4; ++n)
          acc[4 + i][n] = __builtin_amdgcn_mfma_f32_16x16x32_bf16(aQ[i], bX[n], acc[4 + i][n], 0, 0, 0);
      __builtin_amdgcn_s_setprio(0);
      if (t < NT - 1) {
        readB_to(t + 1, bX); readA_to(t + 1, 0, aP);   // batch0(t+1)
        if (t <= NT - 4) { asm volatile("s_waitcnt vmcnt(4)" ::: "memory"); }
        else             { asm volatile("s_waitcnt vmcnt(0)" ::: "memory"); }
        __builtin_amdgcn_s_barrier();      // staging(t+2) visible
      }
    }
  };

  float* red = (float*)(lds + 3 * 32768);  // buffer-3 region
  auto epilogue = [&](int tm) {
    float s[4], q[4];
#pragma unroll
    for (int n = 0; n < 4; ++n) {
      float sv = 0.f, qv = 0.f;
#pragma unroll
      for (int m = 0; m < 8; ++m)
#pragma unroll
        for (int r = 0; r < 4; ++r) {
          float v = acc[m][n][r];
          sv += v; qv += v * v;
        }
      s[n] = sv; q[n] = qv;
    }
#pragma unroll
    for (int n = 0; n < 4; ++n) {
      s[n] += __shfl_xor(s[n], 16); s[n] += __shfl_xor(s[n], 32);
      q[n] += __shfl_xor(q[n], 16); q[n] += __shfl_xor(q[n], 32);
    }
    if (ln < 16) {
#pragma unroll
      for (int n = 0; n < 4; ++n) {
        red[wm * 256 + wn * 64 + n * 16 + ln] = s[n];
        red[512 + wm * 256 + wn * 64 + n * 16 + ln] = q[n];
      }
    }
    __syncthreads();
    if (tid < 256) {
      psum[(size_t)tm * H_DIM + tn * 256 + tid] = red[tid] + red[256 + tid];
    } else {
      int c = tid - 256;
      psqs[(size_t)tm * H_DIM + tn * 256 + c] = red[512 + c] + red[768 + c];
    }
    __syncthreads();   // red consumed; safe for next tile's reuse
    int r0 = tm * 256 + wm * 128 + ((ln >> 4) << 2);
    int c0 = tn * 256 + wn * 64 + (ln & 15);
#pragma unroll
    for (int m = 0; m < 8; ++m)
#pragma unroll
      for (int n = 0; n < 4; ++n) {
        unsigned short* zp = Z + (size_t)(r0 + m * 16) * H_DIM + c0 + n * 16;
#pragma unroll
        for (int r = 0; r < 4; ++r) zp[(size_t)r * H_DIM] = f2bf(acc[m][n][r]);
      }
  };

  // ---- tile 1 ----
  stage(Ap0, 0); stage(Ap0, 1); stage(Ap0, 2);
  asm volatile("s_waitcnt vmcnt(4)" ::: "memory");
  __builtin_amdgcn_s_barrier();
  kloop(Ap0);
  __builtin_amdgcn_s_barrier();            // all reads of bufs done
  // ---- tile 2 staging overlapped with tile-1 epilogue ----
  stage(Ap1, 0); stage(Ap1, 1); stage(Ap1, 2);
  epilogue(tm0);
  asm volatile("s_waitcnt vmcnt(4)" ::: "memory");  // 12 loads (+most stores) retired
  __builtin_amdgcn_s_barrier();
  kloop(Ap1);
  __builtin_amdgcn_s_barrier();
  epilogue(tm0 + 1);
}

// ---------------- BN finalize: cooperative coalesced reduce ----------------
// 32 blocks x 256 threads: block owns 32 channels; 8 j-groups of 16 rows each
// per channel, coalesced 128B row segments, LDS combine. Fixes the round-15
// bottleneck (4 blocks = 16 waves device-wide => ~35 GB/s latency-bound).
__global__ __launch_bounds__(256) void bn_finalize_kernel(
    const float* __restrict__ psum, const float* __restrict__ psqs,
    const float* __restrict__ gamma, const float* __restrict__ beta,
    float* __restrict__ ss) {
  __shared__ float sred[2][8][32];
  int c0 = blockIdx.x * 32;
  int cl = threadIdx.x & 31, jg = threadIdx.x >> 5;
  float s = 0.f, q = 0.f;
#pragma unroll
  for (int j = 0; j < 16; ++j) {
    size_t row = (size_t)(jg * 16 + j) * H_DIM + c0 + cl;
    s += psum[row];
    q += psqs[row];
  }
  sred[0][jg][cl] = s;
  sred[1][jg][cl] = q;
  __syncthreads();
  if (threadIdx.x < 32) {
    int c = threadIdx.x;
    float ts = 0.f, tq = 0.f;
#pragma unroll
    for (int g = 0; g < 8; ++g) { ts += sred[0][g][c]; tq += sred[1][g][c]; }
    const float invN = 1.0f / (float)M_DIM;
    float mean = ts * invN;
    float var = tq * invN - mean * mean;
    float sc = gamma[c0 + c] * rsqrtf(var + 1e-5f);
    ss[c0 + c] = sc;
    ss[H_DIM + c0 + c] = beta[c0 + c] - mean * sc;
  }
}

// ---------------- fused BN-apply + IndRNN recurrence (2 ch/thread, bf16 Z) ----------------
// Round-14 structure (best measured). full=0 (last layer): store ONLY the
// t=255 row - the only slice the classifier reads (saves ~63MB of writes).
// 32-deep static double-buffered prefetch (compile-time indices, rule #20).
__global__ __launch_bounds__(256) void bn_recur_kernel(
    const unsigned short* __restrict__ Z, const float* __restrict__ ss,
    const float* __restrict__ u, unsigned short* __restrict__ Hout, int full) {
  int i2 = blockIdx.x * 256 + threadIdx.x;   // uint pair index, 0..BH/2-1
  int h0 = (i2 & (H_DIM / 2 - 1)) * 2;
  float sc0 = ss[h0], sc1 = ss[h0 + 1];
  float sh0 = ss[H_DIM + h0], sh1 = ss[H_DIM + h0 + 1];
  float u0 = u[h0], u1 = u[h0 + 1];
  float hv0 = 0.f, hv1 = 0.f;

  const size_t ST = BH_DIM / 2;              // uints per t-step
  const unsigned int* Zt = (const unsigned int*)Z + i2;
  unsigned int* Ht = (unsigned int*)Hout + i2;

  unsigned int za[32], zb[32], ho[32];
#pragma unroll
  for (int j = 0; j < 32; ++j) za[j] = Zt[(size_t)j * ST];

#pragma unroll
  for (int blk = 0; blk < 4; ++blk) {
    int tA = blk * 64;
#pragma unroll
    for (int j = 0; j < 32; ++j) zb[j] = Zt[(size_t)(tA + 32 + j) * ST];
#pragma unroll
    for (int j = 0; j < 32; ++j) {
      unsigned int zz = za[j];
      float z0 = fmaf(bf2f((unsigned short)(zz & 0xffffu)), sc0, sh0);
      float z1 = fmaf(bf2f((unsigned short)(zz >> 16)), sc1, sh1);
      hv0 = fmaxf(fmaf(u0, hv0, z0), 0.f);
      hv1 = fmaxf(fmaf(u1, hv1, z1), 0.f);
      ho[j] = pack2bf(hv0, hv1);
    }
#pragma unroll
    for (int j = 0; j < 32; ++j)
      if (full || (tA + j) == T_DIM - 1) Ht[(size_t)(tA + j) * ST] = ho[j];
    if (blk < 3) {
#pragma unroll
      for (int j = 0; j < 32; ++j) za[j] = Zt[(size_t)(tA + 64 + j) * ST];
    }
#pragma unroll
    for (int j = 0; j < 32; ++j) {
      unsigned int zz = zb[j];
      float z0 = fmaf(bf2f((unsigned short)(zz & 0xffffu)), sc0, sh0);
      float z1 = fmaf(bf2f((unsigned short)(zz >> 16)), sc1, sh1);
      hv0 = fmaxf(fmaf(u0, hv0, z0), 0.f);
      hv1 = fmaxf(fmaf(u1, hv1, z1), 0.f);
      ho[j] = pack2bf(hv0, hv1);
    }
#pragma unroll
    for (int j = 0; j < 32; ++j)
      if (full || (tA + 32 + j) == T_DIM - 1) Ht[(size_t)(tA + 32 + j) * ST] = ho[j];
  }
}

// ---------------- classifier: 8 batch-rows per block (Wc reuse x8) ----------------
__global__ __launch_bounds__(256) void classifier_kernel(
    const unsigned short* __restrict__ hlast, const float* __restrict__ Wc,
    const float* __restrict__ bc, float* __restrict__ out) {
  __shared__ float hs[8][H_DIM];            // 32 KB
  int b0 = blockIdx.y * 8;
  int n = blockIdx.x * 256 + threadIdx.x;
#pragma unroll
  for (int r = 0; r < 8; ++r)
    for (int k = threadIdx.x; k < H_DIM; k += 256)
      hs[r][k] = bf2f(hlast[(size_t)(b0 + r) * H_DIM + k]);
  __syncthreads();
  if (n < NC_DIM) {
    float acc[8];
#pragma unroll
    for (int r = 0; r < 8; ++r) acc[r] = bc[n];
#pragma unroll 4
    for (int k = 0; k < H_DIM; ++k) {
      float w = Wc[(size_t)k * NC_DIM + n];
#pragma unroll
      for (int r = 0; r < 8; ++r) acc[r] = fmaf(hs[r][k], w, acc[r]);
    }
#pragma unroll
    for (int r = 0; r < 8; ++r)
      out[(size_t)(b0 + r) * NC_DIM + n] = acc[r];
  }
}

extern "C" void kernel_launch(void* const* d_in, const int* in_sizes, int n_in,
                              void* d_out, int out_size, void* d_ws, size_t ws_size,
                              hipStream_t stream) {
  const float* x     = (const float*)d_in[0];
  const float* W     = (const float*)d_in[1];
  // d_in[2] = b: cancels under BatchNorm (shift-invariant)
  const float* gamma = (const float*)d_in[3];
  const float* beta  = (const float*)d_in[4];
  const float* u     = (const float*)d_in[5];
  const float* Wc    = (const float*)d_in[6];
  const float* bc    = (const float*)d_in[7];
  float* out = (float*)d_out;

  const size_t CH = (size_t)C_DIM * H_DIM;
  const size_t MH = (size_t)M_DIM * H_DIM;
  char* p = (char*)d_ws;
  unsigned short* Wt = (unsigned short*)p; p += L_DIM * CH * sizeof(unsigned short);
  unsigned short* Ha = (unsigned short*)p; p += MH * sizeof(unsigned short);
  unsigned short* Hb = (unsigned short*)p; p += MH * sizeof(unsigned short);
  unsigned short* Z  = (unsigned short*)p; p += MH * sizeof(unsigned short);
  float* psum = (float*)p; p += 128 * H_DIM * sizeof(float);
  float* psqs = (float*)p; p += 128 * H_DIM * sizeof(float);
  float* ss   = (float*)p; p += 2 * H_DIM * sizeof(float);

  f32_to_bf16_kernel<<<2048, 256, 0, stream>>>(x, Ha, (int)(MH / 4));
  wtrans_kernel<<<dim3(H_DIM / 32, C_DIM / 32, L_DIM), dim3(32, 8), 0, stream>>>(W, Wt);

  unsigned short* cur = Ha;
  unsigned short* nxt = Hb;
  for (int l = 0; l < L_DIM; ++l) {
    gemm_kernel<<<256, 512, 131072, stream>>>(cur, Wt + (size_t)l * CH, Z, psum, psqs);
    bn_finalize_kernel<<<32, 256, 0, stream>>>(psum, psqs, gamma + (size_t)l * H_DIM,
                                               beta + (size_t)l * H_DIM, ss);
    bn_recur_kernel<<<BH_DIM / 512, 256, 0, stream>>>(Z, ss, u + (size_t)l * H_DIM, nxt,
                                                      (l < L_DIM - 1) ? 1 : 0);
    unsigned short* tmp = cur; cur = nxt; nxt = tmp;
  }
  classifier_kernel<<<dim3(4, B_DIM / 8), 256, 0, stream>>>(
      cur + (size_t)(T_DIM - 1) * BH_DIM, Wc, bc, out);
}

// Round 17
// 694.266 us; speedup vs baseline: 1.1746x; 1.0839x over previous
//
#include <hip/hip_runtime.h>
#include <hip/hip_bf16.h>

#define T_DIM 256
#define B_DIM 128
#define C_DIM 1024
#define H_DIM 1024
#define L_DIM 6
#define NC_DIM 1000
#define M_DIM (T_DIM * B_DIM)    // 32768
#define BH_DIM (B_DIM * H_DIM)   // 131072

typedef __attribute__((ext_vector_type(8))) short bf16x8;
typedef __attribute__((ext_vector_type(4))) float f32x4;

__device__ __forceinline__ float bf2f(unsigned short u) {
  union { unsigned int i; float f; } v; v.i = ((unsigned int)u) << 16; return v.f;
}
__device__ __forceinline__ unsigned short f2bf(float f) {
  union { float f; unsigned int i; } v; v.f = f;
  unsigned int r = v.i + 0x7fffu + ((v.i >> 16) & 1u);  // RNE
  return (unsigned short)(r >> 16);
}
__device__ __forceinline__ unsigned int pack2bf(float lo, float hi) {
  __hip_bfloat162 b2 = __float22bfloat162_rn(float2{lo, hi});
  union { __hip_bfloat162 b; unsigned int u; } cv; cv.b = b2; return cv.u;
}

__device__ __forceinline__ void gload_lds16(const void* g, void* l) {
  __builtin_amdgcn_global_load_lds(
      (const __attribute__((address_space(1))) unsigned int*)g,
      (__attribute__((address_space(3))) unsigned int*)l, 16, 0, 0);
}

// ---------------- x f32 -> bf16 convert ----------------
__global__ __launch_bounds__(256) void f32_to_bf16_kernel(
    const float* __restrict__ in, unsigned short* __restrict__ out, int n4) {
  int stride = gridDim.x * blockDim.x;
  for (int i = blockIdx.x * blockDim.x + threadIdx.x; i < n4; i += stride) {
    float4 v = ((const float4*)in)[i];
    uint2 o; o.x = pack2bf(v.x, v.y); o.y = pack2bf(v.z, v.w);
    ((uint2*)out)[i] = o;
  }
}

// ---------------- W (L,C,H) f32 -> Wt (L,H,C) bf16 ----------------
__global__ __launch_bounds__(256) void wtrans_kernel(
    const float* __restrict__ W, unsigned short* __restrict__ Wt) {
  __shared__ float tile[32][33];
  int l = blockIdx.z;
  const float* Wl = W + (size_t)l * C_DIM * H_DIM;
  unsigned short* Wtl = Wt + (size_t)l * C_DIM * H_DIM;
  int h0 = blockIdx.x * 32, c0 = blockIdx.y * 32;
  int tx = threadIdx.x, ty = threadIdx.y;  // 32 x 8
#pragma unroll
  for (int i = 0; i < 32; i += 8)
    tile[ty + i][tx] = Wl[(size_t)(c0 + ty + i) * H_DIM + h0 + tx];
  __syncthreads();
#pragma unroll
  for (int i = 0; i < 32; i += 8)
    Wtl[(size_t)(h0 + ty + i) * C_DIM + c0 + tx] = f2bf(tile[tx][ty + i]);
}

// ---------------- GEMM 256x256, BK=32, 4-buffer pipeline, 2 tiles/block ----------------
// (round-11 kernel, unchanged: established ~900 TF plain-HIP structure ceiling)
#define NT 32  // K / 32

__global__ __launch_bounds__(512, 2) void gemm_kernel(
    const unsigned short* __restrict__ A, const unsigned short* __restrict__ Bt,
    unsigned short* __restrict__ Z, float* __restrict__ psum, float* __restrict__ psqs) {
  extern __shared__ char lds[];
  int bid = blockIdx.x;              // 256 blocks, %8==0 -> bijective XCD swizzle
  int swz = (bid & 7) * 32 + (bid >> 3);
  int tm0 = (swz >> 2) * 2;          // tiles (tm0, tn) and (tm0+1, tn)
  int tn = swz & 3;
  int tid = threadIdx.x;
  int wv = tid >> 6, ln = tid & 63;
  int wm = wv >> 2, wn = wv & 3;     // 2 x 4 wave grid

  const char* Ap0 = (const char*)A + (size_t)tm0 * 256 * 2048;        // 2048B = K row
  const char* Ap1 = Ap0 + (size_t)256 * 2048;
  const char* Bpanel = (const char*)Bt + (size_t)tn * 256 * 2048;

  int p0 = wv * 1024 + ln * 16;           // byte within an 8KB (128-row) half
  int l0 = p0 ^ (((p0 >> 7) & 3) << 4);   // involution: chunk ^= (row>>1)&3
  size_t ro0 = (size_t)(p0 >> 6) * 2048 + (l0 & 63);          // rows 0..127
  size_t ro1 = (size_t)(128 + (p0 >> 6)) * 2048 + (l0 & 63);  // rows 128..255
  int sdst = wv * 1024;                   // wave-uniform (+ lane*16 by HW)

  auto stage = [&](const char* Ap, int t) {  // one 32KB K-tile: A 16KB + B 16KB
    char* base = lds + ((t & 3) * 32768);
    int kb = t * 64;                      // 32 k-elems = 64 bytes
    gload_lds16(Ap + ro0 + kb, base + sdst);
    gload_lds16(Ap + ro1 + kb, base + 8192 + sdst);
    gload_lds16(Bpanel + ro0 + kb, base + 16384 + sdst);
    gload_lds16(Bpanel + ro1 + kb, base + 16384 + 8192 + sdst);
  };

  int frow = ln & 15;
  int fchunk = ((ln >> 4) ^ (frow >> 1)) & 3;
  int floff = frow * 64 + (fchunk << 4);

  f32x4 acc[8][4];

  bf16x8 bX[4], aP[4], aQ[4];
  auto readB_to = [&](int t, bf16x8* d) {
    const char* Bb = lds + ((t & 3) * 32768) + 16384 + wn * 4096;
#pragma unroll
    for (int n = 0; n < 4; ++n) d[n] = *(const bf16x8*)(Bb + n * 1024 + floff);
  };
  auto readA_to = [&](int t, int mq, bf16x8* d) {
    const char* Ab = lds + ((t & 3) * 32768) + wm * 8192 + mq * 4096;
#pragma unroll
    for (int i = 0; i < 4; ++i) d[i] = *(const bf16x8*)(Ab + i * 1024 + floff);
  };

  auto kloop = [&](const char* Ap) {
    f32x4 zero = {0.f, 0.f, 0.f, 0.f};
#pragma unroll
    for (int m = 0; m < 8; ++m)
#pragma unroll
      for (int n = 0; n < 4; ++n) acc[m][n] = zero;
    readB_to(0, bX); readA_to(0, 0, aP);
    for (int t = 0; t < NT; ++t) {
      readA_to(t, 1, aQ);                  // batch1: overlaps cluster0 below
      if (t <= NT - 4) stage(Ap, t + 3);
      __builtin_amdgcn_s_setprio(1);
#pragma unroll
      for (int i = 0; i < 4; ++i)
#pragma unroll
        for (int n = 0; n < 4; ++n)
          acc[i][n] = __builtin_amdgcn_mfma_f32_16x16x32_bf16(aP[i], bX[n], acc[i][n], 0, 0, 0);
      __builtin_amdgcn_s_setprio(0);
      __builtin_amdgcn_s_setprio(1);
#pragma unroll
      for (int i = 0; i < 4; ++i)
#pragma unroll
        for (int n = 0; n < 4; ++n)
          acc[4 + i][n] = __builtin_amdgcn_mfma_f32_16x16x32_bf16(aQ[i], bX[n], acc[4 + i][n], 0, 0, 0);
      __builtin_amdgcn_s_setprio(0);
      if (t < NT - 1) {
        readB_to(t + 1, bX); readA_to(t + 1, 0, aP);   // batch0(t+1)
        if (t <= NT - 4) { asm volatile("s_waitcnt vmcnt(4)" ::: "memory"); }
        else             { asm volatile("s_waitcnt vmcnt(0)" ::: "memory"); }
        __builtin_amdgcn_s_barrier();      // staging(t+2) visible
      }
    }
  };

  float* red = (float*)(lds + 3 * 32768);  // buffer-3 region
  auto epilogue = [&](int tm) {
    float s[4], q[4];
#pragma unroll
    for (int n = 0; n < 4; ++n) {
      float sv = 0.f, qv = 0.f;
#pragma unroll
      for (int m = 0; m < 8; ++m)
#pragma unroll
        for (int r = 0; r < 4; ++r) {
          float v = acc[m][n][r];
          sv += v; qv += v * v;
        }
      s[n] = sv; q[n] = qv;
    }
#pragma unroll
    for (int n = 0; n < 4; ++n) {
      s[n] += __shfl_xor(s[n], 16); s[n] += __shfl_xor(s[n], 32);
      q[n] += __shfl_xor(q[n], 16); q[n] += __shfl_xor(q[n], 32);
    }
    if (ln < 16) {
#pragma unroll
      for (int n = 0; n < 4; ++n) {
        red[wm * 256 + wn * 64 + n * 16 + ln] = s[n];
        red[512 + wm * 256 + wn * 64 + n * 16 + ln] = q[n];
      }
    }
    __syncthreads();
    if (tid < 256) {
      psum[(size_t)tm * H_DIM + tn * 256 + tid] = red[tid] + red[256 + tid];
    } else {
      int c = tid - 256;
      psqs[(size_t)tm * H_DIM + tn * 256 + c] = red[512 + c] + red[768 + c];
    }
    __syncthreads();   // red consumed; safe for next tile's reuse
    int r0 = tm * 256 + wm * 128 + ((ln >> 4) << 2);
    int c0 = tn * 256 + wn * 64 + (ln & 15);
#pragma unroll
    for (int m = 0; m < 8; ++m)
#pragma unroll
      for (int n = 0; n < 4; ++n) {
        unsigned short* zp = Z + (size_t)(r0 + m * 16) * H_DIM + c0 + n * 16;
#pragma unroll
        for (int r = 0; r < 4; ++r) zp[(size_t)r * H_DIM] = f2bf(acc[m][n][r]);
      }
  };

  // ---- tile 1 ----
  stage(Ap0, 0); stage(Ap0, 1); stage(Ap0, 2);
  asm volatile("s_waitcnt vmcnt(4)" ::: "memory");
  __builtin_amdgcn_s_barrier();
  kloop(Ap0);
  __builtin_amdgcn_s_barrier();            // all reads of bufs done
  // ---- tile 2 staging overlapped with tile-1 epilogue ----
  stage(Ap1, 0); stage(Ap1, 1); stage(Ap1, 2);
  epilogue(tm0);
  asm volatile("s_waitcnt vmcnt(4)" ::: "memory");  // 12 loads (+most stores) retired
  __builtin_amdgcn_s_barrier();
  kloop(Ap1);
  __builtin_amdgcn_s_barrier();
  epilogue(tm0 + 1);
}

// ---------------- BN finalize: cooperative coalesced reduce (round-16) ----------------
__global__ __launch_bounds__(256) void bn_finalize_kernel(
    const float* __restrict__ psum, const float* __restrict__ psqs,
    const float* __restrict__ gamma, const float* __restrict__ beta,
    float* __restrict__ ss) {
  __shared__ float sred[2][8][32];
  int c0 = blockIdx.x * 32;
  int cl = threadIdx.x & 31, jg = threadIdx.x >> 5;
  float s = 0.f, q = 0.f;
#pragma unroll
  for (int j = 0; j < 16; ++j) {
    size_t row = (size_t)(jg * 16 + j) * H_DIM + c0 + cl;
    s += psum[row];
    q += psqs[row];
  }
  sred[0][jg][cl] = s;
  sred[1][jg][cl] = q;
  __syncthreads();
  if (threadIdx.x < 32) {
    int c = threadIdx.x;
    float ts = 0.f, tq = 0.f;
#pragma unroll
    for (int g = 0; g < 8; ++g) { ts += sred[0][g][c]; tq += sred[1][g][c]; }
    const float invN = 1.0f / (float)M_DIM;
    float mean = ts * invN;
    float var = tq * invN - mean * mean;
    float sc = gamma[c0 + c] * rsqrtf(var + 1e-5f);
    ss[c0 + c] = sc;
    ss[H_DIM + c0 + c] = beta[c0 + c] - mean * sc;
  }
}

// ---------------- fused BN-apply + IndRNN recurrence (round-16: best measured) ----------------
__global__ __launch_bounds__(256) void bn_recur_kernel(
    const unsigned short* __restrict__ Z, const float* __restrict__ ss,
    const float* __restrict__ u, unsigned short* __restrict__ Hout, int full) {
  int i2 = blockIdx.x * 256 + threadIdx.x;   // uint pair index, 0..BH/2-1
  int h0 = (i2 & (H_DIM / 2 - 1)) * 2;
  float sc0 = ss[h0], sc1 = ss[h0 + 1];
  float sh0 = ss[H_DIM + h0], sh1 = ss[H_DIM + h0 + 1];
  float u0 = u[h0], u1 = u[h0 + 1];
  float hv0 = 0.f, hv1 = 0.f;

  const size_t ST = BH_DIM / 2;              // uints per t-step
  const unsigned int* Zt = (const unsigned int*)Z + i2;
  unsigned int* Ht = (unsigned int*)Hout + i2;

  unsigned int za[32], zb[32], ho[32];
#pragma unroll
  for (int j = 0; j < 32; ++j) za[j] = Zt[(size_t)j * ST];

#pragma unroll
  for (int blk = 0; blk < 4; ++blk) {
    int tA = blk * 64;
#pragma unroll
    for (int j = 0; j < 32; ++j) zb[j] = Zt[(size_t)(tA + 32 + j) * ST];
#pragma unroll
    for (int j = 0; j < 32; ++j) {
      unsigned int zz = za[j];
      float z0 = fmaf(bf2f((unsigned short)(zz & 0xffffu)), sc0, sh0);
      float z1 = fmaf(bf2f((unsigned short)(zz >> 16)), sc1, sh1);
      hv0 = fmaxf(fmaf(u0, hv0, z0), 0.f);
      hv1 = fmaxf(fmaf(u1, hv1, z1), 0.f);
      ho[j] = pack2bf(hv0, hv1);
    }
#pragma unroll
    for (int j = 0; j < 32; ++j)
      if (full || (tA + j) == T_DIM - 1) Ht[(size_t)(tA + j) * ST] = ho[j];
    if (blk < 3) {
#pragma unroll
      for (int j = 0; j < 32; ++j) za[j] = Zt[(size_t)(tA + 64 + j) * ST];
    }
#pragma unroll
    for (int j = 0; j < 32; ++j) {
      unsigned int zz = zb[j];
      float z0 = fmaf(bf2f((unsigned short)(zz & 0xffffu)), sc0, sh0);
      float z1 = fmaf(bf2f((unsigned short)(zz >> 16)), sc1, sh1);
      hv0 = fmaxf(fmaf(u0, hv0, z0), 0.f);
      hv1 = fmaxf(fmaf(u1, hv1, z1), 0.f);
      ho[j] = pack2bf(hv0, hv1);
    }
#pragma unroll
    for (int j = 0; j < 32; ++j)
      if (full || (tA + 32 + j) == T_DIM - 1) Ht[(size_t)(tA + 32 + j) * ST] = ho[j];
  }
}

// ---------------- classifier (reverted to proven 1-row/block, 512 blocks) ----------------
__global__ __launch_bounds__(256) void classifier_kernel(
    const unsigned short* __restrict__ hlast, const float* __restrict__ Wc,
    const float* __restrict__ bc, float* __restrict__ out) {
  __shared__ float hs[H_DIM];
  int b = blockIdx.y;
  int n = blockIdx.x * 256 + threadIdx.x;
  for (int k = threadIdx.x; k < H_DIM; k += 256)
    hs[k] = bf2f(hlast[(size_t)b * H_DIM + k]);
  __syncthreads();
  if (n < NC_DIM) {
    float acc = bc[n];
#pragma unroll 8
    for (int k = 0; k < H_DIM; ++k)
      acc = fmaf(hs[k], Wc[(size_t)k * NC_DIM + n], acc);
    out[(size_t)b * NC_DIM + n] = acc;
  }
}

extern "C" void kernel_launch(void* const* d_in, const int* in_sizes, int n_in,
                              void* d_out, int out_size, void* d_ws, size_t ws_size,
                              hipStream_t stream) {
  const float* x     = (const float*)d_in[0];
  const float* W     = (const float*)d_in[1];
  // d_in[2] = b: cancels under BatchNorm (shift-invariant)
  const float* gamma = (const float*)d_in[3];
  const float* beta  = (const float*)d_in[4];
  const float* u     = (const float*)d_in[5];
  const float* Wc    = (const float*)d_in[6];
  const float* bc    = (const float*)d_in[7];
  float* out = (float*)d_out;

  const size_t CH = (size_t)C_DIM * H_DIM;
  const size_t MH = (size_t)M_DIM * H_DIM;
  char* p = (char*)d_ws;
  unsigned short* Wt = (unsigned short*)p; p += L_DIM * CH * sizeof(unsigned short);
  unsigned short* Ha = (unsigned short*)p; p += MH * sizeof(unsigned short);
  unsigned short* Hb = (unsigned short*)p; p += MH * sizeof(unsigned short);
  unsigned short* Z  = (unsigned short*)p; p += MH * sizeof(unsigned short);
  float* psum = (float*)p; p += 128 * H_DIM * sizeof(float);
  float* psqs = (float*)p; p += 128 * H_DIM * sizeof(float);
  float* ss   = (float*)p; p += 2 * H_DIM * sizeof(float);

  f32_to_bf16_kernel<<<2048, 256, 0, stream>>>(x, Ha, (int)(MH / 4));
  wtrans_kernel<<<dim3(H_DIM / 32, C_DIM / 32, L_DIM), dim3(32, 8), 0, stream>>>(W, Wt);

  unsigned short* cur = Ha;
  unsigned short* nxt = Hb;
  for (int l = 0; l < L_DIM; ++l) {
    gemm_kernel<<<256, 512, 131072, stream>>>(cur, Wt + (size_t)l * CH, Z, psum, psqs);
    bn_finalize_kernel<<<32, 256, 0, stream>>>(psum, psqs, gamma + (size_t)l * H_DIM,
                                               beta + (size_t)l * H_DIM, ss);
    bn_recur_kernel<<<BH_DIM / 512, 256, 0, stream>>>(Z, ss, u + (size_t)l * H_DIM, nxt,
                                                      (l < L_DIM - 1) ? 1 : 0);
    unsigned short* tmp = cur; cur = nxt; nxt = tmp;
  }
  classifier_kernel<<<dim3(4, B_DIM), 256, 0, stream>>>(
      cur + (size_t)(T_DIM - 1) * BH_DIM, Wc, bc, out);
}

// Round 18
// 661.375 us; speedup vs baseline: 1.2330x; 1.0497x over previous
//
#include <hip/hip_runtime.h>
#include <hip/hip_bf16.h>

#define T_DIM 256
#define B_DIM 128
#define C_DIM 1024
#define H_DIM 1024
#define L_DIM 6
#define NC_DIM 1000
#define M_DIM (T_DIM * B_DIM)    // 32768
#define BH_DIM (B_DIM * H_DIM)   // 131072

typedef __attribute__((ext_vector_type(8))) short bf16x8;
typedef __attribute__((ext_vector_type(4))) float f32x4;

__device__ __forceinline__ float bf2f(unsigned short u) {
  union { unsigned int i; float f; } v; v.i = ((unsigned int)u) << 16; return v.f;
}
__device__ __forceinline__ unsigned short f2bf(float f) {
  union { float f; unsigned int i; } v; v.f = f;
  unsigned int r = v.i + 0x7fffu + ((v.i >> 16) & 1u);  // RNE
  return (unsigned short)(r >> 16);
}
__device__ __forceinline__ unsigned int pack2bf(float lo, float hi) {
  __hip_bfloat162 b2 = __float22bfloat162_rn(float2{lo, hi});
  union { __hip_bfloat162 b; unsigned int u; } cv; cv.b = b2; return cv.u;
}

__device__ __forceinline__ void gload_lds16(const void* g, void* l) {
  __builtin_amdgcn_global_load_lds(
      (const __attribute__((address_space(1))) unsigned int*)g,
      (__attribute__((address_space(3))) unsigned int*)l, 16, 0, 0);
}

// ---------------- x f32 -> bf16 convert ----------------
__global__ __launch_bounds__(256) void f32_to_bf16_kernel(
    const float* __restrict__ in, unsigned short* __restrict__ out, int n4) {
  int stride = gridDim.x * blockDim.x;
  for (int i = blockIdx.x * blockDim.x + threadIdx.x; i < n4; i += stride) {
    float4 v = ((const float4*)in)[i];
    uint2 o; o.x = pack2bf(v.x, v.y); o.y = pack2bf(v.z, v.w);
    ((uint2*)out)[i] = o;
  }
}

// ---------------- W (L,C,H) f32 -> Wt (L,H,C) bf16 ----------------
__global__ __launch_bounds__(256) void wtrans_kernel(
    const float* __restrict__ W, unsigned short* __restrict__ Wt) {
  __shared__ float tile[32][33];
  int l = blockIdx.z;
  const float* Wl = W + (size_t)l * C_DIM * H_DIM;
  unsigned short* Wtl = Wt + (size_t)l * C_DIM * H_DIM;
  int h0 = blockIdx.x * 32, c0 = blockIdx.y * 32;
  int tx = threadIdx.x, ty = threadIdx.y;  // 32 x 8
#pragma unroll
  for (int i = 0; i < 32; i += 8)
    tile[ty + i][tx] = Wl[(size_t)(c0 + ty + i) * H_DIM + h0 + tx];
  __syncthreads();
#pragma unroll
  for (int i = 0; i < 32; i += 8)
    Wtl[(size_t)(h0 + ty + i) * C_DIM + c0 + tx] = f2bf(tile[tx][ty + i]);
}

// ---------------- GEMM 256x256, BK=64, m201-template 8-phase schedule ----------------
// Z(bf16) = A(bf16, MxK) * Wt(bf16, NxK)^T, fused BN partial stats (f32-exact).
// Full-fidelity port of the verified 256^2 8-phase template (fine phases AND
// deep counted prefetch together - never combined in rounds 2-9):
//  - LDS 128KB = 2 K-tile bufs x {A0,A1,B0,B1} 16KB halves ([128 rows][128B]).
//  - Per K-tile tt, 4 phases: ph_a {read A-mh0 (8) + B-nh0 (4), stage A0(tt+1),
//    lgkmcnt(8)}; ph_b {read B-nh1 (4), stage A1(tt+1)}; ph_c {read A-mh1 (8),
//    stage B0(tt+2)}; ph_d {stage B1(tt+2), vmcnt(4)}. Each phase: barrier ->
//    lgkmcnt(0)+sched_barrier -> setprio + 16 MFMA (one C-quadrant) + barrier.
//  - vmcnt(4) only at ph_d (tail: vmcnt(0) when nothing staged): up to 6
//    half-tiles in flight; every region staged >=1 phase after its last reader
//    (A read ph_a/ph_c, B read ph_a/ph_b - audited), every read's staging
//    retired by the preceding ph_d vmcnt (in-order retirement).
//  - 8-chunk swizzle for 128B rows: chunk ^= row&7 both sides (<=2-way = free).
#define NT 16  // K / 64

__global__ __launch_bounds__(512, 2) void gemm_kernel(
    const unsigned short* __restrict__ A, const unsigned short* __restrict__ Bt,
    unsigned short* __restrict__ Z, float* __restrict__ psum, float* __restrict__ psqs) {
  extern __shared__ char lds[];
  int bid = blockIdx.x;              // 512 blocks, %8==0 -> bijective XCD swizzle
  int swz = (bid & 7) * 64 + (bid >> 3);
  int tm = swz >> 2, tn = swz & 3;   // 128 x 4 tiles
  int tid = threadIdx.x;
  int wv = tid >> 6, ln = tid & 63;
  int wm = wv >> 2, wn = wv & 3;     // 2 x 4 wave grid

  const char* Apanel = (const char*)A + (size_t)tm * 256 * 2048;   // 2048B = K row
  const char* Bpanel = (const char*)Bt + (size_t)tn * 256 * 2048;

  // ---- staging (pre-swizzled global source, linear LDS dest) ----
  // half = 128 rows x 128B; 2 insts/wave-lane (8KB each = 64 rows)
  int srow = wv * 8 + (ln >> 3);                 // row within 64-row group
  int sch  = (ln & 7) ^ (ln >> 3);               // chunk ^= row&7 (row&7 = ln>>3)
  size_t goff = (size_t)srow * 2048 + sch * 16;
  int sdst = wv * 1024;                          // wave-uniform (+ lane*16 by HW)

  auto stageH = [&](int t, int moff, int h) {    // moff: 0=A, 32768=B; h: half
    char* base = lds + (t & 1) * 65536 + moff + h * 16384 + sdst;
    const char* src = (moff ? Bpanel : Apanel) + (size_t)h * 262144 + (size_t)t * 128 + goff;
    gload_lds16(src, base);
    gload_lds16(src + 131072, base + 8192);      // second 64-row group
  };

  // ---- fragment read offsets: row fr=ln&15, chunk (kk*4+fc)^(fr&7), fc=ln>>4
  int fr = ln & 15, fc = ln >> 4;
  int lo0 = fr * 128 + ((fc ^ (fr & 7)) << 4);
  int lo1 = fr * 128 + (((4 + fc) ^ (fr & 7)) << 4);

  f32x4 acc[8][4];
  f32x4 zero = {0.f, 0.f, 0.f, 0.f};
#pragma unroll
  for (int m = 0; m < 8; ++m)
#pragma unroll
    for (int n = 0; n < 4; ++n) acc[m][n] = zero;

  bf16x8 Ar[4][2], B0r[2][2], B1r[2][2];
  auto readA = [&](int t, int mh) {              // wave's A region = A{wm}
    const char* Ab = lds + (t & 1) * 65536 + wm * 16384 + mh * 8192;
#pragma unroll
    for (int m = 0; m < 4; ++m) {
      Ar[m][0] = *(const bf16x8*)(Ab + m * 2048 + lo0);
      Ar[m][1] = *(const bf16x8*)(Ab + m * 2048 + lo1);
    }
  };
  auto readB = [&](int t, int nh, bf16x8 (*Br)[2]) {  // wave's B region = B{wn>>1}
    const char* Bb = lds + (t & 1) * 65536 + 32768 + (wn >> 1) * 16384 +
                     ((wn & 1) * 64 + nh * 32) * 128;
#pragma unroll
    for (int n = 0; n < 2; ++n) {
      Br[n][0] = *(const bf16x8*)(Bb + n * 2048 + lo0);
      Br[n][1] = *(const bf16x8*)(Bb + n * 2048 + lo1);
    }
  };
  auto mfmaQ = [&](int mh, int nh, bf16x8 (*Br)[2]) {  // one C-quadrant, K=64
    __builtin_amdgcn_s_setprio(1);
#pragma unroll
    for (int m = 0; m < 4; ++m)
#pragma unroll
      for (int n = 0; n < 2; ++n)
#pragma unroll
        for (int kk = 0; kk < 2; ++kk)
          acc[mh * 4 + m][nh * 2 + n] = __builtin_amdgcn_mfma_f32_16x16x32_bf16(
              Ar[m][kk], Br[n][kk], acc[mh * 4 + m][nh * 2 + n], 0, 0, 0);
    __builtin_amdgcn_s_setprio(0);
  };

  // prologue: tile0 all 4 halves + tile1 B halves (A halves staged by tt=0 body)
  stageH(0, 0, 0); stageH(0, 0, 1); stageH(0, 32768, 0); stageH(0, 32768, 1);
  stageH(1, 32768, 0); stageH(1, 32768, 1);
  asm volatile("s_waitcnt vmcnt(4)" ::: "memory");   // tile0's 8 loads landed
  __builtin_amdgcn_s_barrier();

  for (int tt = 0; tt < NT; ++tt) {
    // ---- ph_a: quadrant (mh0,nh0) ----
    readA(tt, 0); readB(tt, 0, B0r);               // 12 ds_reads
    if (tt + 1 < NT) stageH(tt + 1, 0, 0);         // A0(tt+1)
    asm volatile("s_waitcnt lgkmcnt(8)" ::: "memory");
    __builtin_amdgcn_s_barrier();
    asm volatile("s_waitcnt lgkmcnt(0)" ::: "memory");
    __builtin_amdgcn_sched_barrier(0);
    mfmaQ(0, 0, B0r);
    __builtin_amdgcn_s_barrier();
    // ---- ph_b: quadrant (mh0,nh1) ----
    readB(tt, 1, B1r);                             // 4 ds_reads
    if (tt + 1 < NT) stageH(tt + 1, 0, 1);         // A1(tt+1)
    __builtin_amdgcn_s_barrier();
    asm volatile("s_waitcnt lgkmcnt(0)" ::: "memory");
    __builtin_amdgcn_sched_barrier(0);
    mfmaQ(0, 1, B1r);
    __builtin_amdgcn_s_barrier();
    // ---- ph_c: quadrant (mh1,nh1) ----
    readA(tt, 1);                                  // 8 ds_reads
    if (tt + 2 < NT) stageH(tt + 2, 32768, 0);     // B0(tt+2)
    __builtin_amdgcn_s_barrier();
    asm volatile("s_waitcnt lgkmcnt(0)" ::: "memory");
    __builtin_amdgcn_sched_barrier(0);
    mfmaQ(1, 1, B1r);
    __builtin_amdgcn_s_barrier();
    // ---- ph_d: quadrant (mh1,nh0) ----
    if (tt + 2 < NT) stageH(tt + 2, 32768, 1);     // B1(tt+2)
    __builtin_amdgcn_s_barrier();
    __builtin_amdgcn_sched_barrier(0);
    mfmaQ(1, 0, B0r);
    if (tt + 2 < NT) { asm volatile("s_waitcnt vmcnt(4)" ::: "memory"); }
    else             { asm volatile("s_waitcnt vmcnt(0)" ::: "memory"); }
    __builtin_amdgcn_s_barrier();
  }

  // ---- epilogue: fused BN partial stats (exact f32) + bf16 Z write ----
  // C/D layout: col = ln&15, row = (ln>>4)*4 + reg
  float s[4], q[4];
#pragma unroll
  for (int n = 0; n < 4; ++n) {
    float sv = 0.f, qv = 0.f;
#pragma unroll
    for (int m = 0; m < 8; ++m)
#pragma unroll
      for (int r = 0; r < 4; ++r) {
        float v = acc[m][n][r];
        sv += v; qv += v * v;
      }
    s[n] = sv; q[n] = qv;
  }
#pragma unroll
  for (int n = 0; n < 4; ++n) {
    s[n] += __shfl_xor(s[n], 16); s[n] += __shfl_xor(s[n], 32);
    q[n] += __shfl_xor(q[n], 16); q[n] += __shfl_xor(q[n], 32);
  }
  float* red = (float*)lds;  // all LDS quiesced after final vmcnt(0)+barrier
  if (ln < 16) {
#pragma unroll
    for (int n = 0; n < 4; ++n) {
      red[wm * 256 + wn * 64 + n * 16 + ln] = s[n];
      red[512 + wm * 256 + wn * 64 + n * 16 + ln] = q[n];
    }
  }
  __syncthreads();
  if (tid < 256) {
    psum[(size_t)tm * H_DIM + tn * 256 + tid] = red[tid] + red[256 + tid];
  } else {
    int c = tid - 256;
    psqs[(size_t)tm * H_DIM + tn * 256 + c] = red[512 + c] + red[768 + c];
  }
  int r0 = tm * 256 + wm * 128 + ((ln >> 4) << 2);
  int c0 = tn * 256 + wn * 64 + (ln & 15);
#pragma unroll
  for (int m = 0; m < 8; ++m)
#pragma unroll
    for (int n = 0; n < 4; ++n) {
      unsigned short* zp = Z + (size_t)(r0 + m * 16) * H_DIM + c0 + n * 16;
#pragma unroll
      for (int r = 0; r < 4; ++r) zp[(size_t)r * H_DIM] = f2bf(acc[m][n][r]);
    }
}

// ---------------- BN finalize: cooperative coalesced reduce ----------------
__global__ __launch_bounds__(256) void bn_finalize_kernel(
    const float* __restrict__ psum, const float* __restrict__ psqs,
    const float* __restrict__ gamma, const float* __restrict__ beta,
    float* __restrict__ ss) {
  __shared__ float sred[2][8][32];
  int c0 = blockIdx.x * 32;
  int cl = threadIdx.x & 31, jg = threadIdx.x >> 5;
  float s = 0.f, q = 0.f;
#pragma unroll
  for (int j = 0; j < 16; ++j) {
    size_t row = (size_t)(jg * 16 + j) * H_DIM + c0 + cl;
    s += psum[row];
    q += psqs[row];
  }
  sred[0][jg][cl] = s;
  sred[1][jg][cl] = q;
  __syncthreads();
  if (threadIdx.x < 32) {
    int c = threadIdx.x;
    float ts = 0.f, tq = 0.f;
#pragma unroll
    for (int g = 0; g < 8; ++g) { ts += sred[0][g][c]; tq += sred[1][g][c]; }
    const float invN = 1.0f / (float)M_DIM;
    float mean = ts * invN;
    float var = tq * invN - mean * mean;
    float sc = gamma[c0 + c] * rsqrtf(var + 1e-5f);
    ss[c0 + c] = sc;
    ss[H_DIM + c0 + c] = beta[c0 + c] - mean * sc;
  }
}

// ---------------- fused BN-apply + IndRNN recurrence (best measured form) ----------------
__global__ __launch_bounds__(256) void bn_recur_kernel(
    const unsigned short* __restrict__ Z, const float* __restrict__ ss,
    const float* __restrict__ u, unsigned short* __restrict__ Hout, int full) {
  int i2 = blockIdx.x * 256 + threadIdx.x;   // uint pair index, 0..BH/2-1
  int h0 = (i2 & (H_DIM / 2 - 1)) * 2;
  float sc0 = ss[h0], sc1 = ss[h0 + 1];
  float sh0 = ss[H_DIM + h0], sh1 = ss[H_DIM + h0 + 1];
  float u0 = u[h0], u1 = u[h0 + 1];
  float hv0 = 0.f, hv1 = 0.f;

  const size_t ST = BH_DIM / 2;              // uints per t-step
  const unsigned int* Zt = (const unsigned int*)Z + i2;
  unsigned int* Ht = (unsigned int*)Hout + i2;

  unsigned int za[32], zb[32], ho[32];
#pragma unroll
  for (int j = 0; j < 32; ++j) za[j] = Zt[(size_t)j * ST];

#pragma unroll
  for (int blk = 0; blk < 4; ++blk) {
    int tA = blk * 64;
#pragma unroll
    for (int j = 0; j < 32; ++j) zb[j] = Zt[(size_t)(tA + 32 + j) * ST];
#pragma unroll
    for (int j = 0; j < 32; ++j) {
      unsigned int zz = za[j];
      float z0 = fmaf(bf2f((unsigned short)(zz & 0xffffu)), sc0, sh0);
      float z1 = fmaf(bf2f((unsigned short)(zz >> 16)), sc1, sh1);
      hv0 = fmaxf(fmaf(u0, hv0, z0), 0.f);
      hv1 = fmaxf(fmaf(u1, hv1, z1), 0.f);
      ho[j] = pack2bf(hv0, hv1);
    }
#pragma unroll
    for (int j = 0; j < 32; ++j)
      if (full || (tA + j) == T_DIM - 1) Ht[(size_t)(tA + j) * ST] = ho[j];
    if (blk < 3) {
#pragma unroll
      for (int j = 0; j < 32; ++j) za[j] = Zt[(size_t)(tA + 64 + j) * ST];
    }
#pragma unroll
    for (int j = 0; j < 32; ++j) {
      unsigned int zz = zb[j];
      float z0 = fmaf(bf2f((unsigned short)(zz & 0xffffu)), sc0, sh0);
      float z1 = fmaf(bf2f((unsigned short)(zz >> 16)), sc1, sh1);
      hv0 = fmaxf(fmaf(u0, hv0, z0), 0.f);
      hv1 = fmaxf(fmaf(u1, hv1, z1), 0.f);
      ho[j] = pack2bf(hv0, hv1);
    }
#pragma unroll
    for (int j = 0; j < 32; ++j)
      if (full || (tA + 32 + j) == T_DIM - 1) Ht[(size_t)(tA + 32 + j) * ST] = ho[j];
  }
}

// ---------------- classifier (proven 1-row/block, 512 blocks) ----------------
__global__ __launch_bounds__(256) void classifier_kernel(
    const unsigned short* __restrict__ hlast, const float* __restrict__ Wc,
    const float* __restrict__ bc, float* __restrict__ out) {
  __shared__ float hs[H_DIM];
  int b = blockIdx.y;
  int n = blockIdx.x * 256 + threadIdx.x;
  for (int k = threadIdx.x; k < H_DIM; k += 256)
    hs[k] = bf2f(hlast[(size_t)b * H_DIM + k]);
  __syncthreads();
  if (n < NC_DIM) {
    float acc = bc[n];
#pragma unroll 8
    for (int k = 0; k < H_DIM; ++k)
      acc = fmaf(hs[k], Wc[(size_t)k * NC_DIM + n], acc);
    out[(size_t)b * NC_DIM + n] = acc;
  }
}

extern "C" void kernel_launch(void* const* d_in, const int* in_sizes, int n_in,
                              void* d_out, int out_size, void* d_ws, size_t ws_size,
                              hipStream_t stream) {
  const float* x     = (const float*)d_in[0];
  const float* W     = (const float*)d_in[1];
  // d_in[2] = b: cancels under BatchNorm (shift-invariant)
  const float* gamma = (const float*)d_in[3];
  const float* beta  = (const float*)d_in[4];
  const float* u     = (const float*)d_in[5];
  const float* Wc    = (const float*)d_in[6];
  const float* bc    = (const float*)d_in[7];
  float* out = (float*)d_out;

  const size_t CH = (size_t)C_DIM * H_DIM;
  const size_t MH = (size_t)M_DIM * H_DIM;
  char* p = (char*)d_ws;
  unsigned short* Wt = (unsigned short*)p; p += L_DIM * CH * sizeof(unsigned short);
  unsigned short* Ha = (unsigned short*)p; p += MH * sizeof(unsigned short);
  unsigned short* Hb = (unsigned short*)p; p += MH * sizeof(unsigned short);
  unsigned short* Z  = (unsigned short*)p; p += MH * sizeof(unsigned short);
  float* psum = (float*)p; p += 128 * H_DIM * sizeof(float);
  float* psqs = (float*)p; p += 128 * H_DIM * sizeof(float);
  float* ss   = (float*)p; p += 2 * H_DIM * sizeof(float);

  f32_to_bf16_kernel<<<2048, 256, 0, stream>>>(x, Ha, (int)(MH / 4));
  wtrans_kernel<<<dim3(H_DIM / 32, C_DIM / 32, L_DIM), dim3(32, 8), 0, stream>>>(W, Wt);

  unsigned short* cur = Ha;
  unsigned short* nxt = Hb;
  for (int l = 0; l < L_DIM; ++l) {
    gemm_kernel<<<(M_DIM / 256) * (H_DIM / 256), 512, 131072, stream>>>(
        cur, Wt + (size_t)l * CH, Z, psum, psqs);
    bn_finalize_kernel<<<32, 256, 0, stream>>>(psum, psqs, gamma + (size_t)l * H_DIM,
                                               beta + (size_t)l * H_DIM, ss);
    bn_recur_kernel<<<BH_DIM / 512, 256, 0, stream>>>(Z, ss, u + (size_t)l * H_DIM, nxt,
                                                      (l < L_DIM - 1) ? 1 : 0);
    unsigned short* tmp = cur; cur = nxt; nxt = tmp;
  }
  classifier_kernel<<<dim3(4, B_DIM), 256, 0, stream>>>(
      cur + (size_t)(T_DIM - 1) * BH_DIM, Wc, bc, out);
}